// Round 1
// baseline (311.849 us; speedup 1.0000x reference)
//
#include <hip/hip_runtime.h>

#define NROWS  32768
#define DDIM   256
#define KCODES 1024

// ---------------------------------------------------------------------------
// kernel 0: codebook row norms, bit-replicating numpy pairwise summation
// (256 = 128+128; each 128: 8 accumulators strided, then
//  ((r0+r1)+(r2+r3))+((r4+r5)+(r6+r7)))
// ---------------------------------------------------------------------------
__global__ void cnorm_np_kernel(const float* __restrict__ cb,
                                float* __restrict__ cnorm) {
    int k = blockIdx.x * blockDim.x + threadIdx.x;
    if (k >= KCODES) return;
    const float* p = cb + (size_t)k * DDIM;
    float halves[2];
    for (int h = 0; h < 2; ++h) {
        const float* a = p + h * 128;
        float r[8];
#pragma unroll
        for (int j = 0; j < 8; ++j) r[j] = __fmul_rn(a[j], a[j]);
        for (int i = 8; i < 128; i += 8) {
#pragma unroll
            for (int j = 0; j < 8; ++j)
                r[j] = __fadd_rn(r[j], __fmul_rn(a[i + j], a[i + j]));
        }
        halves[h] = __fadd_rn(__fadd_rn(__fadd_rn(r[0], r[1]), __fadd_rn(r[2], r[3])),
                              __fadd_rn(__fadd_rn(r[4], r[5]), __fadd_rn(r[6], r[7])));
    }
    cnorm[k] = __fadd_rn(halves[0], halves[1]);
}

// swizzled x-tile accessor: A holds [d][row] with float4-group XOR swizzle
__device__ __forceinline__ float a_at(const float* A, int d, int r) {
    int sw = (d >> 2) & 15;
    return A[d * 64 + ((((r >> 2) ^ sw) << 2) | (r & 3))];
}

// numpy-pairwise ||x_r||^2 from the LDS tile
__device__ __forceinline__ float xnorm_np(const float* A, int r) {
    float halves[2];
    for (int h = 0; h < 2; ++h) {
        float acc8[8];
#pragma unroll
        for (int j = 0; j < 8; ++j) {
            float v = a_at(A, h * 128 + j, r);
            acc8[j] = __fmul_rn(v, v);
        }
        for (int i = 8; i < 128; i += 8) {
#pragma unroll
            for (int j = 0; j < 8; ++j) {
                float v = a_at(A, h * 128 + i + j, r);
                acc8[j] = __fadd_rn(acc8[j], __fmul_rn(v, v));
            }
        }
        halves[h] = __fadd_rn(__fadd_rn(__fadd_rn(acc8[0], acc8[1]), __fadd_rn(acc8[2], acc8[3])),
                              __fadd_rn(__fadd_rn(acc8[4], acc8[5]), __fadd_rn(acc8[6], acc8[7])));
    }
    return __fadd_rn(halves[0], halves[1]);
}

// ---------------------------------------------------------------------------
// main kernel: 64-row tile per block; f32 GEMM (64x64 code tiles, 4x4 micro)
// with per-row top-2 tracking; f64-exact + numpy-rounding-replicated refine;
// gather epilogue.
// ---------------------------------------------------------------------------
__global__ __launch_bounds__(256, 2) void som_main_kernel(
    const float* __restrict__ x, const float* __restrict__ cb,
    const float* __restrict__ cnorm, float* __restrict__ out)
{
    __shared__ __align__(16) float A[16384];  // x tile, [256 d][64 r] swizzled (64 KB)
    __shared__ __align__(16) float B[4096];   // code chunk [64 d][64 c] swizzled (16 KB)

    const int tid = threadIdx.x;
    const int tx  = tid & 15;
    const int ty  = tid >> 4;
    const int row0 = blockIdx.x * 64;
    const float4* cb4 = reinterpret_cast<const float4*>(cb);

    // ---- stage x tile (transposed + swizzled), once ----
    for (int rb = 0; rb < 4; ++rb) {
        int r = rb * 16 + ty;
        const float4* src = reinterpret_cast<const float4*>(x + (size_t)(row0 + r) * DDIM);
#pragma unroll
        for (int j = 0; j < 4; ++j) {
            int d4 = j * 16 + tx;                      // (d>>2); sw = d4&15 = tx
            float4 v = src[d4];
            int col = ((((r >> 2) ^ (d4 & 15)) << 2) | (r & 3));
            A[(d4 * 4 + 0) * 64 + col] = v.x;
            A[(d4 * 4 + 1) * 64 + col] = v.y;
            A[(d4 * 4 + 2) * 64 + col] = v.z;
            A[(d4 * 4 + 3) * 64 + col] = v.w;
        }
    }

    float v1[4], v2[4];
    int   i1[4], i2[4];
#pragma unroll
    for (int i = 0; i < 4; ++i) { v1[i] = 3.0e38f; v2[i] = 3.0e38f; i1[i] = 0; i2[i] = 0; }

    for (int ct = 0; ct < 16; ++ct) {
        float acc[4][4];
#pragma unroll
        for (int i = 0; i < 4; ++i)
#pragma unroll
            for (int j = 0; j < 4; ++j) acc[i][j] = 0.0f;

        for (int dc = 0; dc < 4; ++dc) {
            __syncthreads();  // protect B from previous readers
            // stage B chunk: codes ct*64.., depths dc*64..
#pragma unroll
            for (int p = 0; p < 4; ++p) {
                int cl = p * 16 + ty;
                float4 v = cb4[(size_t)(ct * 64 + cl) * 64 + dc * 16 + tx];
                int col = ((((cl >> 2) ^ tx) << 2) | (cl & 3));   // sw = dl>>2 = tx
                B[(tx * 4 + 0) * 64 + col] = v.x;
                B[(tx * 4 + 1) * 64 + col] = v.y;
                B[(tx * 4 + 2) * 64 + col] = v.z;
                B[(tx * 4 + 3) * 64 + col] = v.w;
            }
            __syncthreads();

            const int abase = dc * 64 * 64;
#pragma unroll
            for (int d4 = 0; d4 < 16; ++d4) {
                const float4* ap = reinterpret_cast<const float4*>(
                    &A[abase + (d4 * 4) * 64 + ((ty ^ d4) << 2)]);
                const float4* bp = reinterpret_cast<const float4*>(
                    &B[(d4 * 4) * 64 + ((tx ^ d4) << 2)]);
#pragma unroll
                for (int u = 0; u < 4; ++u) {
                    float4 av = ap[u * 16];   // +256 B per step: ds_read_b128 offsets
                    float4 bv = bp[u * 16];
                    float aa[4] = {av.x, av.y, av.z, av.w};
                    float bb[4] = {bv.x, bv.y, bv.z, bv.w};
#pragma unroll
                    for (int i = 0; i < 4; ++i)
#pragma unroll
                        for (int j = 0; j < 4; ++j)
                            acc[i][j] = fmaf(aa[i], bb[j], acc[i][j]);
                }
            }
        }

        // ---- per-code-tile epilogue: raw score, per-thread top-2 ----
        float4 cn = reinterpret_cast<const float4*>(cnorm)[ct * 16 + tx];
        float cnl[4] = {cn.x, cn.y, cn.z, cn.w};
#pragma unroll
        for (int i = 0; i < 4; ++i) {
#pragma unroll
            for (int j = 0; j < 4; ++j) {
                float s = cnl[j] - 2.0f * acc[i][j];
                int   c = ct * 64 + tx * 4 + j;     // ascending per thread
                if (s < v1[i])      { v2[i] = v1[i]; i2[i] = i1[i]; v1[i] = s; i1[i] = c; }
                else if (s < v2[i]) { v2[i] = s; i2[i] = c; }
            }
        }
    }

    // ---- cross-tx lexicographic top-2 butterfly merge (16 lanes / row group) ----
#pragma unroll
    for (int i = 0; i < 4; ++i) {
        float av1 = v1[i], av2 = v2[i];
        int   ai1 = i1[i], ai2 = i2[i];
        for (int m = 1; m < 16; m <<= 1) {
            float bv1 = __shfl_xor(av1, m, 64);
            int   bi1 = __shfl_xor(ai1, m, 64);
            float bv2 = __shfl_xor(av2, m, 64);
            int   bi2 = __shfl_xor(ai2, m, 64);
            bool bfirst = (bv1 < av1) || (bv1 == av1 && bi1 < ai1);
            if (bfirst) {
                bool a1lt = (av1 < bv2) || (av1 == bv2 && ai1 < bi2);
                av2 = a1lt ? av1 : bv2;  ai2 = a1lt ? ai1 : bi2;
                av1 = bv1;               ai1 = bi1;
            } else {
                bool b1lt = (bv1 < av2) || (bv1 == av2 && bi1 < ai2);
                av2 = b1lt ? bv1 : av2;  ai2 = b1lt ? bi1 : ai2;
            }
        }
        v1[i] = av1; v2[i] = av2; i1[i] = ai1; i2[i] = ai2;
    }

    // ---- refine: exact f64 dot for both candidates + numpy-rounded decision ----
    __syncthreads();                                  // B no longer read; alias it
    int*   candI = reinterpret_cast<int*>(B);         // [64][2]
    float* candM = B + 128;                           // [64][2]
    float* xns   = B + 256;                           // [64]
    int*   bmu   = reinterpret_cast<int*>(B + 320);   // [64]

    if (tx == 0) {
#pragma unroll
        for (int i = 0; i < 4; ++i) {
            int r = ty * 4 + i;
            candI[r * 2 + 0] = i1[i];
            candI[r * 2 + 1] = i2[i];
        }
    }
    __syncthreads();

    if (tid < 128) {
        int code = candI[tid];
        int r    = tid >> 1;
        const float* crow = cb + (size_t)code * DDIM;
        double m = 0.0;
        for (int d = 0; d < DDIM; ++d)
            m = fma((double)a_at(A, d, r), (double)crow[d], m);
        candM[tid] = (float)m;
    } else if (tid < 192) {
        int r = tid - 128;
        xns[r] = xnorm_np(A, r);
    }
    __syncthreads();

    if (tid < 64) {
        int   c0 = candI[tid * 2 + 0], c1 = candI[tid * 2 + 1];
        float M0 = candM[tid * 2 + 0], M1 = candM[tid * 2 + 1];
        float xn = xns[tid];
        // replicate numpy: (xnorm + cnorm) - 2.0*M, all f32-rounded
        float s0 = __fsub_rn(__fadd_rn(xn, cnorm[c0]), __fmul_rn(2.0f, M0));
        float s1 = __fsub_rn(__fadd_rn(xn, cnorm[c1]), __fmul_rn(2.0f, M1));
        bmu[tid] = (s0 < s1 || (s0 == s1 && c0 < c1)) ? c0 : c1;
    }
    __syncthreads();

    // ---- gather epilogue: out[row] = codebook[bmu[row]] ----
    float4* out4 = reinterpret_cast<float4*>(out);
#pragma unroll
    for (int it = 0; it < 16; ++it) {
        int r    = it * 4 + (tid >> 6);
        int code = bmu[r];
        out4[(size_t)(row0 + r) * 64 + (tid & 63)] = cb4[(size_t)code * 64 + (tid & 63)];
    }
}

extern "C" void kernel_launch(void* const* d_in, const int* in_sizes, int n_in,
                              void* d_out, int out_size, void* d_ws, size_t ws_size,
                              hipStream_t stream) {
    const float* x  = (const float*)d_in[0];
    const float* cb = (const float*)d_in[1];
    float* out   = (float*)d_out;
    float* cnorm = (float*)d_ws;   // 4 KB scratch

    cnorm_np_kernel<<<dim3(4), dim3(256), 0, stream>>>(cb, cnorm);
    som_main_kernel<<<dim3(512), dim3(256), 0, stream>>>(x, cb, cnorm, out);
}

// Round 2
// 102.831 us; speedup vs baseline: 3.0326x; 3.0326x over previous
//
#include <hip/hip_runtime.h>

#define NROWS  32768
#define DDIM   256
#define KCODES 1024

typedef _Float16 half8 __attribute__((ext_vector_type(8)));
typedef float floatx4 __attribute__((ext_vector_type(4)));

// ws layout: [0,4096) f32 cnorm[1024]; [4096, 4096+524288) _Float16 eh[1024*256]
// requires ws_size >= 528384 bytes

// ---------------------------------------------------------------------------
// kernel A: codebook row norms, bit-replicating numpy pairwise summation
// (identical to round-1 version, which passed)
// ---------------------------------------------------------------------------
__global__ void cnorm_np_kernel(const float* __restrict__ cb,
                                float* __restrict__ cnorm) {
    int k = blockIdx.x * blockDim.x + threadIdx.x;
    if (k >= KCODES) return;
    const float* p = cb + (size_t)k * DDIM;
    float halves[2];
    for (int h = 0; h < 2; ++h) {
        const float* a = p + h * 128;
        float r[8];
#pragma unroll
        for (int j = 0; j < 8; ++j) r[j] = __fmul_rn(a[j], a[j]);
        for (int i = 8; i < 128; i += 8) {
#pragma unroll
            for (int j = 0; j < 8; ++j)
                r[j] = __fadd_rn(r[j], __fmul_rn(a[i + j], a[i + j]));
        }
        halves[h] = __fadd_rn(__fadd_rn(__fadd_rn(r[0], r[1]), __fadd_rn(r[2], r[3])),
                              __fadd_rn(__fadd_rn(r[4], r[5]), __fadd_rn(r[6], r[7])));
    }
    cnorm[k] = __fadd_rn(halves[0], halves[1]);
}

// ---------------------------------------------------------------------------
// kernel B: convert codebook f32 -> fp16 (hi only; lo term dropped, error
// absorbed by top-2 + exact refine)
// ---------------------------------------------------------------------------
__global__ void cvt_cb_kernel(const float* __restrict__ cb,
                              _Float16* __restrict__ eh) {
    int idx = blockIdx.x * 512 + threadIdx.x;   // 64 blocks x 512 = 32768 tasks
    int c = idx >> 5, qs = idx & 31;
    const float4* s = reinterpret_cast<const float4*>(cb + (size_t)c * DDIM + qs * 8);
    float4 a = s[0], b = s[1];
    half8 h;
    h[0] = (_Float16)a.x; h[1] = (_Float16)a.y; h[2] = (_Float16)a.z; h[3] = (_Float16)a.w;
    h[4] = (_Float16)b.x; h[5] = (_Float16)b.y; h[6] = (_Float16)b.z; h[7] = (_Float16)b.w;
    *reinterpret_cast<half8*>(eh + (size_t)c * DDIM + qs * 8) = h;
}

// numpy-pairwise ||x||^2 from a global row pointer (same association order as
// the round-1 version that passed)
__device__ __forceinline__ float xnorm_np_g(const float* __restrict__ p) {
    float halves[2];
    for (int h = 0; h < 2; ++h) {
        const float* a = p + h * 128;
        float r[8];
#pragma unroll
        for (int j = 0; j < 8; ++j) r[j] = __fmul_rn(a[j], a[j]);
        for (int i = 8; i < 128; i += 8) {
#pragma unroll
            for (int j = 0; j < 8; ++j)
                r[j] = __fadd_rn(r[j], __fmul_rn(a[i + j], a[i + j]));
        }
        halves[h] = __fadd_rn(__fadd_rn(__fadd_rn(r[0], r[1]), __fadd_rn(r[2], r[3])),
                              __fadd_rn(__fadd_rn(r[4], r[5]), __fadd_rn(r[6], r[7])));
    }
    return __fadd_rn(halves[0], halves[1]);
}

// ---------------------------------------------------------------------------
// main kernel: 128 rows/block, fp16 hi+lo MFMA over all 1024 codes,
// per-lane top-2 tracking, margin fast path + exact refine, gather.
// ---------------------------------------------------------------------------
__global__ __launch_bounds__(512, 2) void som_mfma_kernel(
    const float* __restrict__ x, const float* __restrict__ cb,
    const float* __restrict__ cnorm, const _Float16* __restrict__ eh,
    float* __restrict__ out)
{
    // LDS: XH [128][256] fp16 swizzled (64K) | XL (64K) | E chunk (32K) = 160K
    __shared__ __align__(16) char smem[163840];
    _Float16* XH = reinterpret_cast<_Float16*>(smem);
    _Float16* XL = reinterpret_cast<_Float16*>(smem + 65536);
    char* EB = smem + 131072;

    const int tid  = threadIdx.x;
    const int lane = tid & 63, wid = tid >> 6;
    const int l15  = lane & 15, lq = lane >> 4;
    const int ch   = wid & 3,  rh = wid >> 2;   // code strip (64), row half (64)
    const int row0 = blockIdx.x * 128;

    // ---- prologue: stage E chunk 0 (codes 0..255, depths 0..63) ----
    uint4 epf[4];
#pragma unroll
    for (int p = 0; p < 4; ++p) {
        int idx = p * 512 + tid; int c = idx >> 3, qs = idx & 7;
        epf[p] = *reinterpret_cast<const uint4*>(eh + (size_t)c * DDIM + qs * 8);
    }
#pragma unroll
    for (int p = 0; p < 4; ++p) {
        int idx = p * 512 + tid; int c = idx >> 3, qs = idx & 7;
        *reinterpret_cast<uint4*>(
            EB + (c >> 1) * 256 + ((qs ^ ((c >> 1) & 7)) * 32) + (c & 1) * 16) = epf[p];
    }

    floatx4 acc[4][4];
    float t1[4], t2[4]; int i1[4], i2[4];
#pragma unroll
    for (int r = 0; r < 4; ++r) { t1[r] = -3.0e38f; t2[r] = -3.0e38f; i1[r] = 0; i2[r] = 0; }

    for (int ct = 0; ct < 4; ++ct) {
#pragma unroll
        for (int cf = 0; cf < 4; ++cf)
#pragma unroll
            for (int rf = 0; rf < 4; ++rf)
                acc[cf][rf] = (floatx4){0.f, 0.f, 0.f, 0.f};

        for (int dc = 0; dc < 4; ++dc) {
            const int cc = ct * 4 + dc;

            if (ct == 0) {
                // progressive X staging: slots dc*8 .. dc*8+7 (64 depths)
#pragma unroll
                for (int p = 0; p < 2; ++p) {
                    int idx = p * 512 + tid; int r = idx >> 3, sl = idx & 7;
                    int s = dc * 8 + sl;
                    const float4* src = reinterpret_cast<const float4*>(
                        x + (size_t)(row0 + r) * DDIM + s * 8);
                    float4 a = src[0], b = src[1];
                    float v[8] = {a.x, a.y, a.z, a.w, b.x, b.y, b.z, b.w};
                    half8 hh, hl;
#pragma unroll
                    for (int j = 0; j < 8; ++j) {
                        _Float16 h = (_Float16)v[j];
                        hh[j] = h;
                        hl[j] = (_Float16)(v[j] - (float)h);
                    }
                    int off = (r * 32 + (s ^ (r & 15))) * 8;
                    *reinterpret_cast<half8*>(XH + off) = hh;
                    *reinterpret_cast<half8*>(XL + off) = hl;
                }
            }

            // prefetch next E chunk into registers (latency hides under MFMA)
            if (cc < 15) {
                int ctn = (cc + 1) >> 2, dcn = (cc + 1) & 3;
#pragma unroll
                for (int p = 0; p < 4; ++p) {
                    int idx = p * 512 + tid; int c = idx >> 3, qs = idx & 7;
                    epf[p] = *reinterpret_cast<const uint4*>(
                        eh + (size_t)(ctn * 256 + c) * DDIM + dcn * 64 + qs * 8);
                }
            }

            __syncthreads();   // E(cc) + X(dc) writes visible

#pragma unroll
            for (int ks = 0; ks < 2; ++ks) {
                half8 eF[4], xhf[4], xlf[4];
#pragma unroll
                for (int cf = 0; cf < 4; ++cf) {
                    int cl = ch * 64 + cf * 16 + l15;
                    int q  = ks * 4 + lq;
                    eF[cf] = *reinterpret_cast<const half8*>(
                        EB + (cl >> 1) * 256 + ((q ^ ((cl >> 1) & 7)) * 32) + (cl & 1) * 16);
                }
#pragma unroll
                for (int rf = 0; rf < 4; ++rf) {
                    int r = rh * 64 + rf * 16 + l15;
                    int s = (dc * 2 + ks) * 4 + lq;
                    int off = (r * 32 + (s ^ (r & 15))) * 8;
                    xhf[rf] = *reinterpret_cast<const half8*>(XH + off);
                    xlf[rf] = *reinterpret_cast<const half8*>(XL + off);
                }
#pragma unroll
                for (int cf = 0; cf < 4; ++cf)
#pragma unroll
                    for (int rf = 0; rf < 4; ++rf) {
                        acc[cf][rf] = __builtin_amdgcn_mfma_f32_16x16x32_f16(
                            eF[cf], xhf[rf], acc[cf][rf], 0, 0, 0);
                        acc[cf][rf] = __builtin_amdgcn_mfma_f32_16x16x32_f16(
                            eF[cf], xlf[rf], acc[cf][rf], 0, 0, 0);
                    }
            }

            __syncthreads();   // all waves done reading E(cc)

            if (cc < 15) {     // write prefetched E(cc+1)
#pragma unroll
                for (int p = 0; p < 4; ++p) {
                    int idx = p * 512 + tid; int c = idx >> 3, qs = idx & 7;
                    *reinterpret_cast<uint4*>(
                        EB + (c >> 1) * 256 + ((qs ^ ((c >> 1) & 7)) * 32) + (c & 1) * 16) = epf[p];
                }
            }
        }

        // ---- epilogue ct: q = dot - cnorm/2, per-lane top-2 per row-frag ----
#pragma unroll
        for (int cf = 0; cf < 4; ++cf) {
#pragma unroll
            for (int reg = 0; reg < 4; ++reg) {
                int code = ct * 256 + ch * 64 + cf * 16 + lq * 4 + reg;
                float cn = cnorm[code];
#pragma unroll
                for (int rf = 0; rf < 4; ++rf) {
                    float q = acc[cf][rf][reg] - 0.5f * cn;
                    bool b1 = q > t1[rf], b2 = q > t2[rf];
                    t2[rf] = b1 ? t1[rf] : (b2 ? q : t2[rf]);
                    i2[rf] = b1 ? i1[rf] : (b2 ? code : i2[rf]);
                    t1[rf] = b1 ? q    : t1[rf];
                    i1[rf] = b1 ? code : i1[rf];
                }
            }
        }
    }

    // ---- dump 32 candidates/row into (reused) E region ----
    float* candV = reinterpret_cast<float*>(smem + 131072);           // [128][32]
    int*   candI = reinterpret_cast<int*>(smem + 131072 + 16384);     // [128][32]
#pragma unroll
    for (int rf = 0; rf < 4; ++rf) {
        int r = rh * 64 + rf * 16 + l15;
        int base = r * 32 + ch * 8 + lq * 2;
        candV[base]     = t1[rf]; candI[base]     = i1[rf];
        candV[base + 1] = t2[rf]; candI[base + 1] = i2[rf];
    }
    __syncthreads();

    // ---- per-row decision: margin fast path or exact refine ----
    int* bmu = reinterpret_cast<int*>(smem);   // reuse XH region
    const float THR = 1.0e-2f;                 // s-units; ~25 sigma of approx error
    for (int p = 0; p < 8; ++p) {
        int r = p * 16 + (tid >> 5);
        int j = tid & 31;
        float v  = candV[r * 32 + j];
        int   id = candI[r * 32 + j];

        float V1 = v, V2 = -3.0e38f; int I1 = id, I2 = 0;
#pragma unroll
        for (int m = 1; m < 32; m <<= 1) {
            float pv1 = __shfl_xor(V1, m, 64); int pi1 = __shfl_xor(I1, m, 64);
            float pv2 = __shfl_xor(V2, m, 64); int pi2 = __shfl_xor(I2, m, 64);
            bool sw = pv1 > V1;
            float w1 = sw ? pv1 : V1; int wi1 = sw ? pi1 : I1;
            float lo = sw ? V1 : pv1; int loi = sw ? I1 : pi1;
            float s2 = sw ? pv2 : V2; int s2i = sw ? pi2 : I2;
            bool g = lo > s2;
            V1 = w1; I1 = wi1;
            V2 = g ? lo : s2; I2 = g ? loi : s2i;
        }

        int chosen;
        if (2.0f * (V1 - V2) >= THR) {
            chosen = I1;   // unambiguous winner
        } else {
            // exact: f64 dot + numpy-rounding-replicated score, lex-min
            const float* xr = x + (size_t)(row0 + r) * DDIM;
            const float* cr = cb + (size_t)id * DDIM;
            double m = 0.0;
            for (int d = 0; d < DDIM; ++d)
                m = fma((double)xr[d], (double)cr[d], m);
            float M  = (float)m;
            float xn = xnorm_np_g(xr);
            float s  = __fsub_rn(__fadd_rn(xn, cnorm[id]), __fmul_rn(2.0f, M));
#pragma unroll
            for (int m2 = 1; m2 < 32; m2 <<= 1) {
                float ps = __shfl_xor(s, m2, 64); int pid = __shfl_xor(id, m2, 64);
                bool take = (ps < s) || (ps == s && pid < id);
                s  = take ? ps  : s;
                id = take ? pid : id;
            }
            chosen = id;
        }
        if (j == 0) bmu[r] = chosen;
    }
    __syncthreads();

    // ---- gather: out[row] = codebook[bmu[row]] ----
    float4* out4 = reinterpret_cast<float4*>(out);
    const float4* cb4 = reinterpret_cast<const float4*>(cb);
#pragma unroll
    for (int p = 0; p < 16; ++p) {
        int idx = p * 512 + tid;
        int r = idx >> 6, sl = idx & 63;
        int code = bmu[r];
        out4[(size_t)(row0 + r) * 64 + sl] = cb4[(size_t)code * 64 + sl];
    }
}

extern "C" void kernel_launch(void* const* d_in, const int* in_sizes, int n_in,
                              void* d_out, int out_size, void* d_ws, size_t ws_size,
                              hipStream_t stream) {
    const float* x  = (const float*)d_in[0];
    const float* cb = (const float*)d_in[1];
    float* out = (float*)d_out;

    float*    cnorm = (float*)d_ws;
    _Float16* eh    = (_Float16*)((char*)d_ws + 4096);

    cnorm_np_kernel<<<dim3(4), dim3(256), 0, stream>>>(cb, cnorm);
    cvt_cb_kernel<<<dim3(64), dim3(512), 0, stream>>>(cb, eh);
    som_mfma_kernel<<<dim3(256), dim3(512), 0, stream>>>(x, cb, cnorm, eh, out);
}